// Round 23
// baseline (121.177 us; speedup 1.0000x reference)
//
#include <hip/hip_runtime.h>

#define N_NODES 50000
#define D 128
#define N_EDGES 800000
#define SCAN_BLOCKS ((N_NODES + 255) / 256)   // 196
#define GEMM_BLOCKS ((N_NODES + 63) / 64)     // 782
#define BINS 196                              // ceil(50000/256) row bins
#define NB1 64                                // pass-1 blocks per support
#define CH1 12500                             // edges per pass-1 block
#define NKEY 2048                             // 256 rows x 8 col-segments
#define WTB 128                               // wt_build blocks fused into p1

typedef __attribute__((ext_vector_type(8))) short short8;
typedef __attribute__((ext_vector_type(4))) float f32x4;
typedef __attribute__((ext_vector_type(2))) float f32x2;

__device__ __forceinline__ unsigned short f2bf(float f) {
    unsigned u = __builtin_bit_cast(unsigned, f);
    u += 0x7FFFu + ((u >> 16) & 1u);
    return (unsigned short)(u >> 16);
}
__device__ __forceinline__ float bflo(unsigned p) {
    return __builtin_bit_cast(float, p << 16);
}
__device__ __forceinline__ float bfhi(unsigned p) {
    return __builtin_bit_cast(float, p & 0xFFFF0000u);
}

// ---- gemm body (global-read variant, fallback tiers only) ----
template<int NS>
__device__ __forceinline__ void gemm_body(const float* __restrict__ x,
                                          const unsigned short* __restrict__ wt,
                                          unsigned short* __restrict__ pre0,
                                          unsigned short* __restrict__ pre1,
                                          int n_rows, int blk) {
    const int lane = threadIdx.x & 63;
    const int wid  = threadIdx.x >> 6;
    const int q    = lane >> 4;
    const int rlo  = lane & 15;
    const int r0   = blk * 64 + wid * 16;
    if (r0 >= n_rows) return;

    const float4* x4 = (const float4*)x;
    int arow  = r0 + rlo;
    int arowc = arow < n_rows ? arow : n_rows - 1;

    short8 afr[4];
    #pragma unroll
    for (int kb = 0; kb < 4; ++kb) {
        float4 fa = x4[(size_t)arowc * 32 + kb * 8 + q * 2];
        float4 fb = x4[(size_t)arowc * 32 + kb * 8 + q * 2 + 1];
        short8 a;
        a[0] = (short)f2bf(fa.x); a[1] = (short)f2bf(fa.y);
        a[2] = (short)f2bf(fa.z); a[3] = (short)f2bf(fa.w);
        a[4] = (short)f2bf(fb.x); a[5] = (short)f2bf(fb.y);
        a[6] = (short)f2bf(fb.z); a[7] = (short)f2bf(fb.w);
        afr[kb] = a;
    }

    const short8* wt8 = (const short8*)wt;
    f32x4 acc[NS][8];
    #pragma unroll
    for (int s = 0; s < NS; ++s)
        #pragma unroll
        for (int t = 0; t < 8; ++t)
            acc[s][t] = (f32x4){0.f, 0.f, 0.f, 0.f};

    #pragma unroll
    for (int t = 0; t < 8; ++t) {
        int c = t * 16 + rlo;
        #pragma unroll
        for (int kb = 0; kb < 4; ++kb) {
            short8 b0 = wt8[(size_t)c * 16 + kb * 4 + q];
            acc[0][t] = __builtin_amdgcn_mfma_f32_16x16x32_bf16(afr[kb], b0, acc[0][t], 0, 0, 0);
            if (NS == 2) {
                short8 b1 = wt8[(size_t)(D + c) * 16 + kb * 4 + q];
                acc[NS - 1][t] = __builtin_amdgcn_mfma_f32_16x16x32_bf16(afr[kb], b1, acc[NS - 1][t], 0, 0, 0);
            }
        }
    }

    #pragma unroll
    for (int i = 0; i < 4; ++i) {
        int rw = r0 + q * 4 + i;
        if (rw < n_rows) {
            #pragma unroll
            for (int t = 0; t < 8; ++t) {
                pre0[(size_t)rw * D + t * 16 + rlo] = f2bf(acc[0][t][i]);
                if (NS == 2) pre1[(size_t)rw * D + t * 16 + rlo] = f2bf(acc[NS - 1][t][i]);
            }
        }
    }
}

// ======================= radix CSR build (no global atomics) =======================

__global__ __launch_bounds__(256) void p1_count_wt(const int* __restrict__ r0,
                                                   const int* __restrict__ r1,
                                                   int* __restrict__ h,
                                                   const float* __restrict__ w,
                                                   unsigned short* __restrict__ wt) {
    int bid = blockIdx.x;
    if (bid < 2 * NB1) {
        int s = bid & 1, blk = bid >> 1;
        const int* r = s ? r1 : r0;
        __shared__ int hist[BINS];
        for (int i = threadIdx.x; i < BINS; i += 256) hist[i] = 0;
        __syncthreads();
        int start = blk * CH1, end = start + CH1;
        for (int e = start + (int)threadIdx.x; e < end; e += 256)
            atomicAdd(&hist[r[e] >> 8], 1);
        __syncthreads();
        for (int i = threadIdx.x; i < BINS; i += 256)
            h[(size_t)(s * NB1 + blk) * BINS + i] = hist[i];
    } else {
        int i = (bid - 2 * NB1) * 256 + threadIdx.x;
        if (i < 2 * D * D) {
            int s = i >> 14, rem = i & 16383, c = rem >> 7, k = rem & 127;
            wt[i] = f2bf(w[s * D * D + k * D + c]);
        }
    }
}

__global__ __launch_bounds__(256) void binredscan(const int* __restrict__ h,
                                                  int* __restrict__ binbase) {
    int s = blockIdx.x, t = threadIdx.x;
    int acc[8] = {0, 0, 0, 0, 0, 0, 0, 0};
    if (t < BINS) {
        for (int blk = 0; blk < NB1; blk += 8) {
            #pragma unroll
            for (int j = 0; j < 8; ++j)
                acc[j] += h[(size_t)(s * NB1 + blk + j) * BINS + t];
        }
    }
    int v = acc[0] + acc[1] + acc[2] + acc[3] + acc[4] + acc[5] + acc[6] + acc[7];
    const int lane = t & 63, wid = t >> 6;
    __shared__ int ws[4];
    int incl = v;
    #pragma unroll
    for (int o = 1; o < 64; o <<= 1) { int tv = __shfl_up(incl, o); if (lane >= o) incl += tv; }
    if (lane == 63) ws[wid] = incl;
    __syncthreads();
    int wbase = 0;
    #pragma unroll
    for (int j = 0; j < 4; ++j) wbase += (j < wid) ? ws[j] : 0;
    int excl = wbase + incl - v;
    if (t < BINS) binbase[s * (BINS + 1) + t] = excl;
    if (t == BINS - 1) binbase[s * (BINS + 1) + BINS] = excl + v;
}

__global__ __launch_bounds__(64) void blkscan(int* __restrict__ h,
                                              const int* __restrict__ binbase) {
    int s = blockIdx.y, bin = blockIdx.x, t = threadIdx.x;
    size_t idx = (size_t)(s * NB1 + t) * BINS + bin;
    int v = h[idx];
    int incl = v;
    #pragma unroll
    for (int o = 1; o < 64; o <<= 1) { int tv = __shfl_up(incl, o); if (t >= o) incl += tv; }
    h[idx] = binbase[s * (BINS + 1) + bin] + (incl - v);
}

// k_fill_gemm: [fill blocks | gemm blocks (ONE support staged at a time)]
#define LWT_STRIDE 17
__global__ __launch_bounds__(256) void k_fill_gemm(const float* __restrict__ x,
                                                   const unsigned short* __restrict__ wt,
                                                   unsigned short* __restrict__ pre0,
                                                   unsigned short* __restrict__ pre1,
                                                   const int* __restrict__ r0, const int* __restrict__ c0,
                                                   const float* __restrict__ v0,
                                                   const int* __restrict__ r1, const int* __restrict__ c1,
                                                   const float* __restrict__ v1,
                                                   const int* __restrict__ h,
                                                   int2* __restrict__ rec, int n_rows) {
    __shared__ int base[BINS];
    __shared__ int cnt2[BINS];
    __shared__ short8 lwt[D * LWT_STRIDE];   // 34.8 KB (one support)
    int bid = blockIdx.x;
    if (bid < 2 * NB1) {
        int s = bid & 1, blk = bid >> 1;
        const int*   r = s ? r1 : r0;
        const int*   c = s ? c1 : c0;
        const float* v = s ? v1 : v0;
        int2* rs = rec + (size_t)s * N_EDGES;
        for (int i = threadIdx.x; i < BINS; i += 256) {
            base[i] = h[(size_t)(s * NB1 + blk) * BINS + i];
            cnt2[i] = 0;
        }
        __syncthreads();
        int start = blk * CH1, end = start + CH1;
        for (int e = start + (int)threadIdx.x; e < end; e += 256) {
            int rr = r[e], cc = c[e];
            float vv = v[e];
            int bin = rr >> 8;
            int lr = atomicAdd(&cnt2[bin], 1);
            rs[base[bin] + lr] = make_int2((cc << 8) | (rr & 255), __float_as_int(vv));
        }
    } else {
        int blk = bid - 2 * NB1;
        const int lane = threadIdx.x & 63;
        const int wid  = threadIdx.x >> 6;
        const int q    = lane >> 4;
        const int rlo  = lane & 15;
        const int r0g  = blk * 64 + wid * 16;
        const float4* x4 = (const float4*)x;

        short8 afr[4];
        {
            int arow  = r0g + rlo;
            int arowc = arow < n_rows ? (arow < 0 ? 0 : arow) : n_rows - 1;
            #pragma unroll
            for (int kb = 0; kb < 4; ++kb) {
                float4 fa = x4[(size_t)arowc * 32 + kb * 8 + q * 2];
                float4 fb = x4[(size_t)arowc * 32 + kb * 8 + q * 2 + 1];
                short8 a;
                a[0] = (short)f2bf(fa.x); a[1] = (short)f2bf(fa.y);
                a[2] = (short)f2bf(fa.z); a[3] = (short)f2bf(fa.w);
                a[4] = (short)f2bf(fb.x); a[5] = (short)f2bf(fb.y);
                a[6] = (short)f2bf(fb.z); a[7] = (short)f2bf(fb.w);
                afr[kb] = a;
            }
        }

        #pragma unroll
        for (int s = 0; s < 2; ++s) {
            const short8* wg = (const short8*)wt + (size_t)s * D * 16;
            if (s) __syncthreads();
            for (int i = threadIdx.x; i < D * 16; i += 256) {
                int cc = i >> 4, ee = i & 15;
                lwt[cc * LWT_STRIDE + ee] = wg[i];
            }
            __syncthreads();

            if (r0g < n_rows) {
                f32x4 acc[8];
                #pragma unroll
                for (int t = 0; t < 8; ++t) acc[t] = (f32x4){0.f, 0.f, 0.f, 0.f};
                #pragma unroll
                for (int t = 0; t < 8; ++t) {
                    int c = t * 16 + rlo;
                    #pragma unroll
                    for (int kb = 0; kb < 4; ++kb) {
                        short8 b = lwt[c * LWT_STRIDE + kb * 4 + q];
                        acc[t] = __builtin_amdgcn_mfma_f32_16x16x32_bf16(afr[kb], b, acc[t], 0, 0, 0);
                    }
                }
                unsigned short* pre = s ? pre1 : pre0;
                #pragma unroll
                for (int i = 0; i < 4; ++i) {
                    int rw = r0g + q * 4 + i;
                    if (rw < n_rows) {
                        #pragma unroll
                        for (int t = 0; t < 8; ++t)
                            pre[(size_t)rw * D + t * 16 + rlo] = f2bf(acc[t][i]);
                    }
                }
            }
        }
    }
}

// p2: per (bin,support) counting sort, key = (row_low8<<3)|col_seg; ep packed 4B.
__global__ __launch_bounds__(512) void p2_sort(const int* __restrict__ binbase,
                                               const int2* __restrict__ rec,
                                               unsigned* __restrict__ ep,
                                               int* __restrict__ off) {
    int s = blockIdx.y, bin = blockIdx.x, t = threadIdx.x;
    int bs  = binbase[s * (BINS + 1) + bin];
    int be  = binbase[s * (BINS + 1) + bin + 1];
    int cnt = be - bs;
    const int2* rs = rec + (size_t)s * N_EDGES;
    unsigned* es = ep + (size_t)s * N_EDGES;
    __shared__ int lc[NKEY];
    __shared__ int cur[NKEY];
    __shared__ int ws[8];
    #pragma unroll
    for (int j = 0; j < NKEY / 512; ++j) lc[t + j * 512] = 0;
    __syncthreads();
    for (int i = t; i < cnt; i += 512) {
        int2 R = rs[bs + i];
        int col = R.x >> 8;
        int key = ((R.x & 255) << 3) | (col >> 13);
        atomicAdd(&lc[key], 1);
    }
    __syncthreads();
    int kb = t * 4;
    int s0 = lc[kb], s1 = lc[kb + 1], s2 = lc[kb + 2], s3 = lc[kb + 3];
    int tot = s0 + s1 + s2 + s3;
    const int lane = t & 63, wid = t >> 6;
    int incl = tot;
    #pragma unroll
    for (int o = 1; o < 64; o <<= 1) { int tv = __shfl_up(incl, o); if (lane >= o) incl += tv; }
    if (lane == 63) ws[wid] = incl;
    __syncthreads();
    int wbase = 0;
    #pragma unroll
    for (int j = 0; j < 8; ++j) wbase += (j < wid) ? ws[j] : 0;
    int excl = wbase + incl - tot;
    cur[kb]     = excl;
    cur[kb + 1] = excl + s0;
    cur[kb + 2] = excl + s0 + s1;
    cur[kb + 3] = excl + s0 + s1 + s2;
    if ((t & 1) == 0) {
        int row = bin * 256 + (t >> 1);
        if (row < N_NODES) off[s * (N_NODES + 1) + row] = bs + excl;
    }
    if (bin == 0 && t == 0) off[s * (N_NODES + 1) + N_NODES] = N_EDGES;
    __syncthreads();
    for (int i = t; i < cnt; i += 512) {
        int2 R = rs[bs + i];
        int col = R.x >> 8;
        int key = ((R.x & 255) << 3) | (col >> 13);
        int p = atomicAdd(&cur[key], 1);
        es[bs + p] = ((unsigned)col << 16) | (unsigned)f2bf(__int_as_float(R.y));
    }
}

// ======================= gather: 2 adjacent rows x 2 supports = 4 streams/wave =======================
__device__ __forceinline__ void row_acc4(const unsigned* __restrict__ ep,
                                         const unsigned* __restrict__ prew,
                                         int b, int e, int lane, float& ax, float& ay) {
    int i = b;
    for (; i + 7 < e; i += 8) {
        unsigned E[8], P[8];
        #pragma unroll
        for (int j = 0; j < 8; ++j) E[j] = ep[i + j];
        #pragma unroll
        for (int j = 0; j < 8; ++j) P[j] = prew[(size_t)(E[j] >> 16) * 64 + lane];
        #pragma unroll
        for (int j = 0; j < 8; ++j) {
            float w = bflo(E[j]);
            ax = fmaf(w, bflo(P[j]), ax);
            ay = fmaf(w, bfhi(P[j]), ay);
        }
    }
    if (i + 3 < e) {
        unsigned E[4], P[4];
        #pragma unroll
        for (int j = 0; j < 4; ++j) E[j] = ep[i + j];
        #pragma unroll
        for (int j = 0; j < 4; ++j) P[j] = prew[(size_t)(E[j] >> 16) * 64 + lane];
        #pragma unroll
        for (int j = 0; j < 4; ++j) {
            float w = bflo(E[j]);
            ax = fmaf(w, bflo(P[j]), ax);
            ay = fmaf(w, bfhi(P[j]), ay);
        }
        i += 4;
    }
    for (; i < e; ++i) {
        unsigned E = ep[i];
        float w = bflo(E);
        unsigned p = prew[(size_t)(E >> 16) * 64 + lane];
        ax = fmaf(w, bflo(p), ax);
        ay = fmaf(w, bfhi(p), ay);
    }
}

__device__ __forceinline__ void pair_acc4(const unsigned* __restrict__ ep0, const unsigned* __restrict__ ep1,
                                          const unsigned* __restrict__ pre0w,
                                          const unsigned* __restrict__ pre1w,
                                          int& i0, int e0, int& i1, int e1, int lane,
                                          float& ax0, float& ay0, float& ax1, float& ay1) {
    while (i0 + 3 < e0 && i1 + 3 < e1) {
        unsigned E0[4], E1[4], P0[4], P1[4];
        #pragma unroll
        for (int j = 0; j < 4; ++j) { E0[j] = ep0[i0 + j]; E1[j] = ep1[i1 + j]; }
        #pragma unroll
        for (int j = 0; j < 4; ++j) {
            P0[j] = pre0w[(size_t)(E0[j] >> 16) * 64 + lane];
            P1[j] = pre1w[(size_t)(E1[j] >> 16) * 64 + lane];
        }
        #pragma unroll
        for (int j = 0; j < 4; ++j) {
            float w0 = bflo(E0[j]);
            float w1 = bflo(E1[j]);
            ax0 = fmaf(w0, bflo(P0[j]), ax0);
            ay0 = fmaf(w0, bfhi(P0[j]), ay0);
            ax1 = fmaf(w1, bflo(P1[j]), ax1);
            ay1 = fmaf(w1, bfhi(P1[j]), ay1);
        }
        i0 += 4; i1 += 4;
    }
}

__global__ __launch_bounds__(256) void gather_fused4(const int* __restrict__ off_base,
                                                     const unsigned* __restrict__ ep_base,
                                                     const unsigned short* __restrict__ pre0,
                                                     const unsigned short* __restrict__ pre1,
                                                     float* __restrict__ out, int n_rows) {
    const int lane = threadIdx.x & 63;
    const int wid  = threadIdx.x >> 6;
    const int wpg  = 4 * gridDim.x;
    const unsigned* ep1b = ep_base + N_EDGES;
    const int* o0 = off_base;
    const int* o1 = off_base + (N_NODES + 1);
    const unsigned* pre0w = (const unsigned*)pre0;
    const unsigned* pre1w = (const unsigned*)pre1;
    f32x2* out2 = (f32x2*)out;
    const int npair = n_rows >> 1;   // 25000

    for (int p = blockIdx.x * 4 + wid; p < npair; p += wpg) {
        int ra = 2 * p, rb = ra + 1;   // adjacent rows: shared L2 locality
        int i0 = __builtin_amdgcn_readfirstlane(o0[ra]);
        int e0 = __builtin_amdgcn_readfirstlane(o0[ra + 1]);
        int i1 = __builtin_amdgcn_readfirstlane(o1[ra]);
        int e1 = __builtin_amdgcn_readfirstlane(o1[ra + 1]);
        int i2 = e0;                    // o0[rb] == e0 (contiguous CSR)
        int e2 = __builtin_amdgcn_readfirstlane(o0[rb + 1]);
        int i3 = e1;
        int e3 = __builtin_amdgcn_readfirstlane(o1[rb + 1]);

        float ax0 = 0.f, ay0 = 0.f, ax1 = 0.f, ay1 = 0.f;
        float ax2 = 0.f, ay2 = 0.f, ax3 = 0.f, ay3 = 0.f;

        // quad joint: 16 loads in flight
        while (i0 + 3 < e0 && i1 + 3 < e1 && i2 + 3 < e2 && i3 + 3 < e3) {
            unsigned E0[4], E1[4], E2[4], E3[4];
            unsigned P0[4], P1[4], P2[4], P3[4];
            #pragma unroll
            for (int j = 0; j < 4; ++j) {
                E0[j] = ep_base[i0 + j]; E1[j] = ep1b[i1 + j];
                E2[j] = ep_base[i2 + j]; E3[j] = ep1b[i3 + j];
            }
            #pragma unroll
            for (int j = 0; j < 4; ++j) {
                P0[j] = pre0w[(size_t)(E0[j] >> 16) * 64 + lane];
                P1[j] = pre1w[(size_t)(E1[j] >> 16) * 64 + lane];
                P2[j] = pre0w[(size_t)(E2[j] >> 16) * 64 + lane];
                P3[j] = pre1w[(size_t)(E3[j] >> 16) * 64 + lane];
            }
            #pragma unroll
            for (int j = 0; j < 4; ++j) {
                float w0 = bflo(E0[j]), w1 = bflo(E1[j]);
                float w2 = bflo(E2[j]), w3 = bflo(E3[j]);
                ax0 = fmaf(w0, bflo(P0[j]), ax0); ay0 = fmaf(w0, bfhi(P0[j]), ay0);
                ax1 = fmaf(w1, bflo(P1[j]), ax1); ay1 = fmaf(w1, bfhi(P1[j]), ay1);
                ax2 = fmaf(w2, bflo(P2[j]), ax2); ay2 = fmaf(w2, bfhi(P2[j]), ay2);
                ax3 = fmaf(w3, bflo(P3[j]), ax3); ay3 = fmaf(w3, bfhi(P3[j]), ay3);
            }
            i0 += 4; i1 += 4; i2 += 4; i3 += 4;
        }
        // pair tails (per row: both supports jointly, 8 in flight)
        pair_acc4(ep_base, ep1b, pre0w, pre1w, i0, e0, i1, e1, lane, ax0, ay0, ax1, ay1);
        pair_acc4(ep_base, ep1b, pre0w, pre1w, i2, e2, i3, e3, lane, ax2, ay2, ax3, ay3);
        row_acc4(ep_base, pre0w, i0, e0, lane, ax0, ay0);
        row_acc4(ep1b,    pre1w, i1, e1, lane, ax1, ay1);
        row_acc4(ep_base, pre0w, i2, e2, lane, ax2, ay2);
        row_acc4(ep1b,    pre1w, i3, e3, lane, ax3, ay3);

        f32x2 oA, oB;
        oA.x = fmaxf(ax0 + ax1, 0.f);
        oA.y = fmaxf(ay0 + ay1, 0.f);
        oB.x = fmaxf(ax2 + ax3, 0.f);
        oB.y = fmaxf(ay2 + ay3, 0.f);
        __builtin_nontemporal_store(oA, &out2[(size_t)ra * 64 + lane]);
        __builtin_nontemporal_store(oB, &out2[(size_t)rb * 64 + lane]);
    }
}

// ======================= fallback path (proven pieces, int2 ep) =======================
__global__ __launch_bounds__(256) void wt_build(const float* __restrict__ w,
                                                unsigned short* __restrict__ wt) {
    int i = blockIdx.x * 256 + threadIdx.x;
    if (i < 2 * D * D) {
        int s = i >> 14, rem = i & 16383, c = rem >> 7, k = rem & 127;
        wt[i] = f2bf(w[s * D * D + k * D + c]);
    }
}

__device__ __forceinline__ void row_acc(const int2* __restrict__ ep,
                                        const unsigned short* __restrict__ pre,
                                        int b, int e, int lane, float& ax, float& ay) {
    int i = b;
    for (; i + 7 < e; i += 8) {
        int2 E[8];
        unsigned P[8];
        #pragma unroll
        for (int j = 0; j < 8; ++j) E[j] = ep[i + j];
        #pragma unroll
        for (int j = 0; j < 8; ++j) P[j] = *(const unsigned*)(pre + (size_t)E[j].x * D + 2 * lane);
        #pragma unroll
        for (int j = 0; j < 8; ++j) {
            float w = __int_as_float(E[j].y);
            ax = fmaf(w, bflo(P[j]), ax);
            ay = fmaf(w, bfhi(P[j]), ay);
        }
    }
    for (; i < e; ++i) {
        int2 e0 = ep[i];
        float w = __int_as_float(e0.y);
        unsigned p = *(const unsigned*)(pre + (size_t)e0.x * D + 2 * lane);
        ax = fmaf(w, bflo(p), ax);
        ay = fmaf(w, bfhi(p), ay);
    }
}

__global__ __launch_bounds__(256) void gather_fused(const int* __restrict__ off_base,
                                                    const int2* __restrict__ ep_base,
                                                    const unsigned short* __restrict__ pre0,
                                                    const unsigned short* __restrict__ pre1,
                                                    float* __restrict__ out, int n_rows) {
    const int lane = threadIdx.x & 63;
    const int wid  = threadIdx.x >> 6;
    const int wpg  = 4 * gridDim.x;
    const int2* ep1b = ep_base + N_EDGES;
    const int* o1 = off_base + (N_NODES + 1);
    float2* out2 = (float2*)out;
    for (int r = blockIdx.x * 4 + wid; r < n_rows; r += wpg) {
        float ax0 = 0.f, ay0 = 0.f, ax1 = 0.f, ay1 = 0.f;
        row_acc(ep_base, pre0, off_base[r], off_base[r + 1], lane, ax0, ay0);
        row_acc(ep1b,    pre1, o1[r], o1[r + 1], lane, ax1, ay1);
        float2 o;
        o.x = fmaxf(ax0 + ax1, 0.f);
        o.y = fmaxf(ay0 + ay1, 0.f);
        out2[(size_t)r * 64 + lane] = o;
    }
}

__global__ __launch_bounds__(256) void gemm_mfma2(const float* __restrict__ x,
                                                  const unsigned short* __restrict__ wt,
                                                  unsigned short* __restrict__ pre0,
                                                  unsigned short* __restrict__ pre1, int n_rows) {
    gemm_body<2>(x, wt, pre0, pre1, n_rows, blockIdx.x);
}
__global__ __launch_bounds__(256) void gemm_mfma1(const float* __restrict__ x,
                                                  const unsigned short* __restrict__ wt,
                                                  unsigned short* __restrict__ pre, int n_rows) {
    gemm_body<1>(x, wt, pre, pre, n_rows, blockIdx.x);
}

__global__ __launch_bounds__(256) void hist_rank(const int* __restrict__ r0,
                                                 const int* __restrict__ r1,
                                                 int* __restrict__ cnt_base,
                                                 int* __restrict__ rank_base, int n_edges) {
    int s = blockIdx.y;
    const int* r = s ? r1 : r0;
    int* cnt  = cnt_base + s * N_NODES;
    int* rank = rank_base + (size_t)s * N_EDGES;
    for (int e = blockIdx.x * 256 + threadIdx.x; e < n_edges; e += gridDim.x * 256)
        rank[e] = atomicAdd(&cnt[r[e]], 1);
}

__global__ __launch_bounds__(256) void scanA(const int* __restrict__ cnt_base,
                                             int* __restrict__ bsum) {
    int s = blockIdx.y;
    int i = blockIdx.x * 256 + threadIdx.x;
    int v = (i < N_NODES) ? cnt_base[s * N_NODES + i] : 0;
    const int lane = threadIdx.x & 63;
    const int wid  = threadIdx.x >> 6;
    __shared__ int ws[4];
    #pragma unroll
    for (int off = 32; off > 0; off >>= 1) v += __shfl_down(v, off);
    if (lane == 0) ws[wid] = v;
    __syncthreads();
    if (threadIdx.x == 0)
        bsum[s * SCAN_BLOCKS + blockIdx.x] = ws[0] + ws[1] + ws[2] + ws[3];
}

__global__ __launch_bounds__(256) void scanC2(const int* __restrict__ cnt_base,
                                              const int* __restrict__ bsum,
                                              int* __restrict__ off_base) {
    int s = blockIdx.y;
    int t = threadIdx.x;
    const int lane = t & 63;
    const int wid  = t >> 6;
    __shared__ int ws[4];
    __shared__ int base_s;
    int bv = (t < (int)blockIdx.x && t < SCAN_BLOCKS) ? bsum[s * SCAN_BLOCKS + t] : 0;
    #pragma unroll
    for (int off = 32; off > 0; off >>= 1) bv += __shfl_down(bv, off);
    if (lane == 0) ws[wid] = bv;
    __syncthreads();
    if (t == 0) base_s = ws[0] + ws[1] + ws[2] + ws[3];
    __syncthreads();
    int base = base_s;
    __syncthreads();
    int i = blockIdx.x * 256 + t;
    int v = (i < N_NODES) ? cnt_base[s * N_NODES + i] : 0;
    int incl = v;
    #pragma unroll
    for (int off = 1; off < 64; off <<= 1) {
        int tv = __shfl_up(incl, off);
        if (lane >= off) incl += tv;
    }
    if (lane == 63) ws[wid] = incl;
    __syncthreads();
    int wbase = 0;
    #pragma unroll
    for (int j = 0; j < 4; ++j) wbase += (j < wid) ? ws[j] : 0;
    int* off = off_base + s * (N_NODES + 1);
    if (i < N_NODES)
        off[i] = base + wbase + incl - v;
    if (blockIdx.x == 0 && t == 0)
        off[N_NODES] = N_EDGES;
}

__global__ __launch_bounds__(256) void scatter_csr(const int* __restrict__ r0, const int* __restrict__ c0,
                                                   const float* __restrict__ v0,
                                                   const int* __restrict__ r1, const int* __restrict__ c1,
                                                   const float* __restrict__ v1,
                                                   const int* __restrict__ off_base,
                                                   const int* __restrict__ rank_base,
                                                   int2* __restrict__ ep_base, int n_edges) {
    int s = blockIdx.y;
    const int*   r    = s ? r1 : r0;
    const int*   c    = s ? c1 : c0;
    const float* v    = s ? v1 : v0;
    const int*   off  = off_base + s * (N_NODES + 1);
    const int*   rank = rank_base + (size_t)s * N_EDGES;
    int2* ep = ep_base + (size_t)s * N_EDGES;
    for (int e = blockIdx.x * 256 + threadIdx.x; e < n_edges; e += gridDim.x * 256) {
        int p = off[r[e]] + rank[e];
        int2 rec;
        rec.x = c[e];
        rec.y = __float_as_int(v[e]);
        ep[p] = rec;
    }
}

template<int ACCUM_RELU>
__global__ __launch_bounds__(256) void gather_one(const int* __restrict__ off,
                                                  const int2* __restrict__ ep,
                                                  const unsigned short* __restrict__ pre,
                                                  float* __restrict__ out, int n_rows) {
    const int lane = threadIdx.x & 63;
    const int wid  = threadIdx.x >> 6;
    const int wpg  = 4 * gridDim.x;
    float2* out2 = (float2*)out;
    for (int r = blockIdx.x * 4 + wid; r < n_rows; r += wpg) {
        float ax = 0.f, ay = 0.f;
        row_acc(ep, pre, off[r], off[r + 1], lane, ax, ay);
        float2 o;
        if (ACCUM_RELU) {
            float2 prev = out2[(size_t)r * 64 + lane];
            o.x = fmaxf(prev.x + ax, 0.f);
            o.y = fmaxf(prev.y + ay, 0.f);
        } else {
            o.x = ax; o.y = ay;
        }
        out2[(size_t)r * 64 + lane] = o;
    }
}

extern "C" void kernel_launch(void* const* d_in, const int* in_sizes, int n_in,
                              void* d_out, int out_size, void* d_ws, size_t ws_size,
                              hipStream_t stream) {
    const float* x       = (const float*)d_in[0];
    const float* weights = (const float*)d_in[1];
    const int*   ei0     = (const int*)d_in[2];
    const float* v0      = (const float*)d_in[3];
    const int*   ei1     = (const int*)d_in[4];
    const float* v1      = (const float*)d_in[5];
    float* out = (float*)d_out;

    dim3 blk(256);
    const size_t PRE_B = (size_t)N_NODES * D * sizeof(unsigned short);  // 12.8 MB
    const size_t WT_B  = (size_t)2 * D * D * sizeof(unsigned short);    // 64 KB
    const size_t H_B   = (size_t)2 * NB1 * BINS * 4;                    // 100 KB
    const size_t BB_B  = (size_t)2 * (BINS + 1) * 4;
    const size_t OFF_B = (size_t)2 * (N_NODES + 1) * 4;
    const size_t E8    = (size_t)2 * N_EDGES * sizeof(int2);            // 12.8 MB
    const size_t E4    = (size_t)2 * N_EDGES * 4;                       // 6.4 MB

    char* wsb = (char*)d_ws;
    size_t needNew = 2 * PRE_B + WT_B + H_B + BB_B + OFF_B + E8 + E4;
    size_t needA1 = 2 * PRE_B + WT_B
                  + (size_t)(2 * (N_NODES + 1) + 2 * N_NODES + 2 * SCAN_BLOCKS) * 4
                  + E8 + (size_t)2 * N_EDGES * 4;

    if (ws_size >= needNew) {
        unsigned short* pre0 = (unsigned short*)wsb;
        unsigned short* pre1 = (unsigned short*)(wsb + PRE_B);
        unsigned short* wt   = (unsigned short*)(wsb + 2 * PRE_B);
        int*  h       = (int*)(wsb + 2 * PRE_B + WT_B);
        int*  binbase = (int*)((char*)h + H_B);
        int*  off     = (int*)((char*)binbase + BB_B);
        int2* rec     = (int2*)((char*)off + OFF_B);
        unsigned* ep  = (unsigned*)(rec + (size_t)2 * N_EDGES);

        p1_count_wt<<<2 * NB1 + WTB, blk, 0, stream>>>(ei0, ei1, h, weights, wt);
        binredscan<<<2, blk, 0, stream>>>(h, binbase);
        blkscan<<<dim3(BINS, 2), dim3(64), 0, stream>>>(h, binbase);
        k_fill_gemm<<<2 * NB1 + GEMM_BLOCKS, blk, 0, stream>>>(
            x, wt, pre0, pre1,
            ei0, ei0 + N_EDGES, v0, ei1, ei1 + N_EDGES, v1,
            h, rec, N_NODES);
        p2_sort<<<dim3(BINS, 2), dim3(512), 0, stream>>>(binbase, rec, ep, off);
        gather_fused4<<<6250, blk, 0, stream>>>(off, ep, pre0, pre1, out, N_NODES);
    } else if (ws_size >= needA1) {
        unsigned short* pre0 = (unsigned short*)wsb;
        unsigned short* pre1 = (unsigned short*)(wsb + PRE_B);
        unsigned short* wt   = (unsigned short*)(wsb + 2 * PRE_B);
        int*  off  = (int*)(wsb + 2 * PRE_B + WT_B);
        int*  cnt  = off + 2 * (N_NODES + 1);
        int*  bsum = cnt + 2 * N_NODES;
        int2* ep   = (int2*)(bsum + 2 * SCAN_BLOCKS);
        int*  rank = (int*)(ep + (size_t)2 * N_EDGES);

        hipMemsetAsync(cnt, 0, (size_t)2 * N_NODES * sizeof(int), stream);
        wt_build<<<128, blk, 0, stream>>>(weights, wt);
        hist_rank<<<dim3(1024, 2), blk, 0, stream>>>(ei0, ei1, cnt, rank, N_EDGES);
        gemm_mfma2<<<GEMM_BLOCKS, blk, 0, stream>>>(x, wt, pre0, pre1, N_NODES);
        scanA<<<dim3(SCAN_BLOCKS, 2), blk, 0, stream>>>(cnt, bsum);
        scanC2<<<dim3(SCAN_BLOCKS, 2), blk, 0, stream>>>(cnt, bsum, off);
        scatter_csr<<<dim3(1024, 2), blk, 0, stream>>>(ei0, ei0 + N_EDGES, v0,
                                                       ei1, ei1 + N_EDGES, v1,
                                                       off, rank, ep, N_EDGES);
        gather_fused<<<12500, blk, 0, stream>>>(off, ep, pre0, pre1, out, N_NODES);
    } else {
        unsigned short* pre = (unsigned short*)wsb;
        unsigned short* wt  = (unsigned short*)(wsb + PRE_B);
        int*  off  = (int*)(wsb + PRE_B + WT_B);
        int*  cnt  = off + (N_NODES + 1);
        int*  bsum = cnt + N_NODES;
        int2* ep   = (int2*)(bsum + SCAN_BLOCKS);
        int*  rank = (int*)pre;

        wt_build<<<128, blk, 0, stream>>>(weights, wt);
        const int* rows[2] = {ei0, ei1};
        const int* cols[2] = {ei0 + N_EDGES, ei1 + N_EDGES};
        const float* vals[2] = {v0, v1};
        for (int s = 0; s < 2; ++s) {
            hipMemsetAsync(cnt, 0, (size_t)N_NODES * sizeof(int), stream);
            hist_rank<<<dim3(1024, 1), blk, 0, stream>>>(rows[s], rows[s], cnt, rank, N_EDGES);
            scanA<<<dim3(SCAN_BLOCKS, 1), blk, 0, stream>>>(cnt, bsum);
            scanC2<<<dim3(SCAN_BLOCKS, 1), blk, 0, stream>>>(cnt, bsum, off);
            scatter_csr<<<dim3(1024, 1), blk, 0, stream>>>(rows[s], cols[s], vals[s],
                                                           rows[s], cols[s], vals[s],
                                                           off, rank, ep, N_EDGES);
            gemm_mfma1<<<GEMM_BLOCKS, blk, 0, stream>>>(x, wt + (size_t)s * D * D, pre, N_NODES);
            if (s == 0)
                gather_one<0><<<12500, blk, 0, stream>>>(off, ep, pre, out, N_NODES);
            else
                gather_one<1><<<12500, blk, 0, stream>>>(off, ep, pre, out, N_NODES);
        }
    }
}

// Round 24
// 119.688 us; speedup vs baseline: 1.0124x; 1.0124x over previous
//
#include <hip/hip_runtime.h>

#define N_NODES 50000
#define D 128
#define N_EDGES 800000
#define SCAN_BLOCKS ((N_NODES + 255) / 256)   // 196
#define GEMM_BLOCKS ((N_NODES + 63) / 64)     // 782
#define BINS 196                              // ceil(50000/256) row bins
#define NB1 64                                // pass-1 blocks per support
#define CH1 12500                             // edges per pass-1 block
#define NKEY 2048                             // 256 rows x 8 col-segments
#define WTB 128                               // wt_build blocks fused into p1

typedef __attribute__((ext_vector_type(8))) short short8;
typedef __attribute__((ext_vector_type(4))) float f32x4;
typedef __attribute__((ext_vector_type(2))) float f32x2;

__device__ __forceinline__ unsigned short f2bf(float f) {
    unsigned u = __builtin_bit_cast(unsigned, f);
    u += 0x7FFFu + ((u >> 16) & 1u);
    return (unsigned short)(u >> 16);
}
__device__ __forceinline__ float bflo(unsigned p) {
    return __builtin_bit_cast(float, p << 16);
}
__device__ __forceinline__ float bfhi(unsigned p) {
    return __builtin_bit_cast(float, p & 0xFFFF0000u);
}

// ---- gemm body (global-read variant, fallback tiers only) ----
template<int NS>
__device__ __forceinline__ void gemm_body(const float* __restrict__ x,
                                          const unsigned short* __restrict__ wt,
                                          unsigned short* __restrict__ pre0,
                                          unsigned short* __restrict__ pre1,
                                          int n_rows, int blk) {
    const int lane = threadIdx.x & 63;
    const int wid  = threadIdx.x >> 6;
    const int q    = lane >> 4;
    const int rlo  = lane & 15;
    const int r0   = blk * 64 + wid * 16;
    if (r0 >= n_rows) return;

    const float4* x4 = (const float4*)x;
    int arow  = r0 + rlo;
    int arowc = arow < n_rows ? arow : n_rows - 1;

    short8 afr[4];
    #pragma unroll
    for (int kb = 0; kb < 4; ++kb) {
        float4 fa = x4[(size_t)arowc * 32 + kb * 8 + q * 2];
        float4 fb = x4[(size_t)arowc * 32 + kb * 8 + q * 2 + 1];
        short8 a;
        a[0] = (short)f2bf(fa.x); a[1] = (short)f2bf(fa.y);
        a[2] = (short)f2bf(fa.z); a[3] = (short)f2bf(fa.w);
        a[4] = (short)f2bf(fb.x); a[5] = (short)f2bf(fb.y);
        a[6] = (short)f2bf(fb.z); a[7] = (short)f2bf(fb.w);
        afr[kb] = a;
    }

    const short8* wt8 = (const short8*)wt;
    f32x4 acc[NS][8];
    #pragma unroll
    for (int s = 0; s < NS; ++s)
        #pragma unroll
        for (int t = 0; t < 8; ++t)
            acc[s][t] = (f32x4){0.f, 0.f, 0.f, 0.f};

    #pragma unroll
    for (int t = 0; t < 8; ++t) {
        int c = t * 16 + rlo;
        #pragma unroll
        for (int kb = 0; kb < 4; ++kb) {
            short8 b0 = wt8[(size_t)c * 16 + kb * 4 + q];
            acc[0][t] = __builtin_amdgcn_mfma_f32_16x16x32_bf16(afr[kb], b0, acc[0][t], 0, 0, 0);
            if (NS == 2) {
                short8 b1 = wt8[(size_t)(D + c) * 16 + kb * 4 + q];
                acc[NS - 1][t] = __builtin_amdgcn_mfma_f32_16x16x32_bf16(afr[kb], b1, acc[NS - 1][t], 0, 0, 0);
            }
        }
    }

    #pragma unroll
    for (int i = 0; i < 4; ++i) {
        int rw = r0 + q * 4 + i;
        if (rw < n_rows) {
            #pragma unroll
            for (int t = 0; t < 8; ++t) {
                pre0[(size_t)rw * D + t * 16 + rlo] = f2bf(acc[0][t][i]);
                if (NS == 2) pre1[(size_t)rw * D + t * 16 + rlo] = f2bf(acc[NS - 1][t][i]);
            }
        }
    }
}

// ======================= radix CSR build (no global atomics) =======================

__global__ __launch_bounds__(256) void p1_count_wt(const int* __restrict__ r0,
                                                   const int* __restrict__ r1,
                                                   int* __restrict__ h,
                                                   const float* __restrict__ w,
                                                   unsigned short* __restrict__ wt) {
    int bid = blockIdx.x;
    if (bid < 2 * NB1) {
        int s = bid & 1, blk = bid >> 1;
        const int* r = s ? r1 : r0;
        __shared__ int hist[BINS];
        for (int i = threadIdx.x; i < BINS; i += 256) hist[i] = 0;
        __syncthreads();
        int start = blk * CH1, end = start + CH1;
        for (int e = start + (int)threadIdx.x; e < end; e += 256)
            atomicAdd(&hist[r[e] >> 8], 1);
        __syncthreads();
        for (int i = threadIdx.x; i < BINS; i += 256)
            h[(size_t)(s * NB1 + blk) * BINS + i] = hist[i];
    } else {
        int i = (bid - 2 * NB1) * 256 + threadIdx.x;
        if (i < 2 * D * D) {
            int s = i >> 14, rem = i & 16383, c = rem >> 7, k = rem & 127;
            wt[i] = f2bf(w[s * D * D + k * D + c]);
        }
    }
}

__global__ __launch_bounds__(256) void binredscan(const int* __restrict__ h,
                                                  int* __restrict__ binbase) {
    int s = blockIdx.x, t = threadIdx.x;
    int acc[8] = {0, 0, 0, 0, 0, 0, 0, 0};
    if (t < BINS) {
        for (int blk = 0; blk < NB1; blk += 8) {
            #pragma unroll
            for (int j = 0; j < 8; ++j)
                acc[j] += h[(size_t)(s * NB1 + blk + j) * BINS + t];
        }
    }
    int v = acc[0] + acc[1] + acc[2] + acc[3] + acc[4] + acc[5] + acc[6] + acc[7];
    const int lane = t & 63, wid = t >> 6;
    __shared__ int ws[4];
    int incl = v;
    #pragma unroll
    for (int o = 1; o < 64; o <<= 1) { int tv = __shfl_up(incl, o); if (lane >= o) incl += tv; }
    if (lane == 63) ws[wid] = incl;
    __syncthreads();
    int wbase = 0;
    #pragma unroll
    for (int j = 0; j < 4; ++j) wbase += (j < wid) ? ws[j] : 0;
    int excl = wbase + incl - v;
    if (t < BINS) binbase[s * (BINS + 1) + t] = excl;
    if (t == BINS - 1) binbase[s * (BINS + 1) + BINS] = excl + v;
}

__global__ __launch_bounds__(64) void blkscan(int* __restrict__ h,
                                              const int* __restrict__ binbase) {
    int s = blockIdx.y, bin = blockIdx.x, t = threadIdx.x;
    size_t idx = (size_t)(s * NB1 + t) * BINS + bin;
    int v = h[idx];
    int incl = v;
    #pragma unroll
    for (int o = 1; o < 64; o <<= 1) { int tv = __shfl_up(incl, o); if (t >= o) incl += tv; }
    h[idx] = binbase[s * (BINS + 1) + bin] + (incl - v);
}

// k_fill_gemm: [fill blocks | gemm blocks (ONE support staged at a time)]
#define LWT_STRIDE 17
__global__ __launch_bounds__(256) void k_fill_gemm(const float* __restrict__ x,
                                                   const unsigned short* __restrict__ wt,
                                                   unsigned short* __restrict__ pre0,
                                                   unsigned short* __restrict__ pre1,
                                                   const int* __restrict__ r0, const int* __restrict__ c0,
                                                   const float* __restrict__ v0,
                                                   const int* __restrict__ r1, const int* __restrict__ c1,
                                                   const float* __restrict__ v1,
                                                   const int* __restrict__ h,
                                                   int2* __restrict__ rec, int n_rows) {
    __shared__ int base[BINS];
    __shared__ int cnt2[BINS];
    __shared__ short8 lwt[D * LWT_STRIDE];   // 34.8 KB (one support)
    int bid = blockIdx.x;
    if (bid < 2 * NB1) {
        int s = bid & 1, blk = bid >> 1;
        const int*   r = s ? r1 : r0;
        const int*   c = s ? c1 : c0;
        const float* v = s ? v1 : v0;
        int2* rs = rec + (size_t)s * N_EDGES;
        for (int i = threadIdx.x; i < BINS; i += 256) {
            base[i] = h[(size_t)(s * NB1 + blk) * BINS + i];
            cnt2[i] = 0;
        }
        __syncthreads();
        int start = blk * CH1, end = start + CH1;
        for (int e = start + (int)threadIdx.x; e < end; e += 256) {
            int rr = r[e], cc = c[e];
            float vv = v[e];
            int bin = rr >> 8;
            int lr = atomicAdd(&cnt2[bin], 1);
            rs[base[bin] + lr] = make_int2((cc << 8) | (rr & 255), __float_as_int(vv));
        }
    } else {
        int blk = bid - 2 * NB1;
        const int lane = threadIdx.x & 63;
        const int wid  = threadIdx.x >> 6;
        const int q    = lane >> 4;
        const int rlo  = lane & 15;
        const int r0g  = blk * 64 + wid * 16;
        const float4* x4 = (const float4*)x;

        short8 afr[4];
        {
            int arow  = r0g + rlo;
            int arowc = arow < n_rows ? (arow < 0 ? 0 : arow) : n_rows - 1;
            #pragma unroll
            for (int kb = 0; kb < 4; ++kb) {
                float4 fa = x4[(size_t)arowc * 32 + kb * 8 + q * 2];
                float4 fb = x4[(size_t)arowc * 32 + kb * 8 + q * 2 + 1];
                short8 a;
                a[0] = (short)f2bf(fa.x); a[1] = (short)f2bf(fa.y);
                a[2] = (short)f2bf(fa.z); a[3] = (short)f2bf(fa.w);
                a[4] = (short)f2bf(fb.x); a[5] = (short)f2bf(fb.y);
                a[6] = (short)f2bf(fb.z); a[7] = (short)f2bf(fb.w);
                afr[kb] = a;
            }
        }

        #pragma unroll
        for (int s = 0; s < 2; ++s) {
            const short8* wg = (const short8*)wt + (size_t)s * D * 16;
            if (s) __syncthreads();
            for (int i = threadIdx.x; i < D * 16; i += 256) {
                int cc = i >> 4, ee = i & 15;
                lwt[cc * LWT_STRIDE + ee] = wg[i];
            }
            __syncthreads();

            if (r0g < n_rows) {
                f32x4 acc[8];
                #pragma unroll
                for (int t = 0; t < 8; ++t) acc[t] = (f32x4){0.f, 0.f, 0.f, 0.f};
                #pragma unroll
                for (int t = 0; t < 8; ++t) {
                    int c = t * 16 + rlo;
                    #pragma unroll
                    for (int kb = 0; kb < 4; ++kb) {
                        short8 b = lwt[c * LWT_STRIDE + kb * 4 + q];
                        acc[t] = __builtin_amdgcn_mfma_f32_16x16x32_bf16(afr[kb], b, acc[t], 0, 0, 0);
                    }
                }
                unsigned short* pre = s ? pre1 : pre0;
                #pragma unroll
                for (int i = 0; i < 4; ++i) {
                    int rw = r0g + q * 4 + i;
                    if (rw < n_rows) {
                        #pragma unroll
                        for (int t = 0; t < 8; ++t)
                            pre[(size_t)rw * D + t * 16 + rlo] = f2bf(acc[t][i]);
                    }
                }
            }
        }
    }
}

// p2: per (bin,support) counting sort, key = (row_low8<<3)|col_seg; ep packed 4B.
__global__ __launch_bounds__(512) void p2_sort(const int* __restrict__ binbase,
                                               const int2* __restrict__ rec,
                                               unsigned* __restrict__ ep,
                                               int* __restrict__ off) {
    int s = blockIdx.y, bin = blockIdx.x, t = threadIdx.x;
    int bs  = binbase[s * (BINS + 1) + bin];
    int be  = binbase[s * (BINS + 1) + bin + 1];
    int cnt = be - bs;
    const int2* rs = rec + (size_t)s * N_EDGES;
    unsigned* es = ep + (size_t)s * N_EDGES;
    __shared__ int lc[NKEY];
    __shared__ int cur[NKEY];
    __shared__ int ws[8];
    #pragma unroll
    for (int j = 0; j < NKEY / 512; ++j) lc[t + j * 512] = 0;
    __syncthreads();
    for (int i = t; i < cnt; i += 512) {
        int2 R = rs[bs + i];
        int col = R.x >> 8;
        int key = ((R.x & 255) << 3) | (col >> 13);
        atomicAdd(&lc[key], 1);
    }
    __syncthreads();
    int kb = t * 4;
    int s0 = lc[kb], s1 = lc[kb + 1], s2 = lc[kb + 2], s3 = lc[kb + 3];
    int tot = s0 + s1 + s2 + s3;
    const int lane = t & 63, wid = t >> 6;
    int incl = tot;
    #pragma unroll
    for (int o = 1; o < 64; o <<= 1) { int tv = __shfl_up(incl, o); if (lane >= o) incl += tv; }
    if (lane == 63) ws[wid] = incl;
    __syncthreads();
    int wbase = 0;
    #pragma unroll
    for (int j = 0; j < 8; ++j) wbase += (j < wid) ? ws[j] : 0;
    int excl = wbase + incl - tot;
    cur[kb]     = excl;
    cur[kb + 1] = excl + s0;
    cur[kb + 2] = excl + s0 + s1;
    cur[kb + 3] = excl + s0 + s1 + s2;
    if ((t & 1) == 0) {
        int row = bin * 256 + (t >> 1);
        if (row < N_NODES) off[s * (N_NODES + 1) + row] = bs + excl;
    }
    if (bin == 0 && t == 0) off[s * (N_NODES + 1) + N_NODES] = N_EDGES;
    __syncthreads();
    for (int i = t; i < cnt; i += 512) {
        int2 R = rs[bs + i];
        int col = R.x >> 8;
        int key = ((R.x & 255) << 3) | (col >> 13);
        int p = atomicAdd(&cur[key], 1);
        es[bs + p] = ((unsigned)col << 16) | (unsigned)f2bf(__int_as_float(R.y));
    }
}

// ======================= gather (R22 proven: 1 row/wave, dual-support joint-8) =======================
__device__ __forceinline__ void row_acc4(const unsigned* __restrict__ ep,
                                         const unsigned* __restrict__ prew,
                                         int b, int e, int lane, float& ax, float& ay) {
    int i = b;
    for (; i + 7 < e; i += 8) {
        unsigned E[8], P[8];
        #pragma unroll
        for (int j = 0; j < 8; ++j) E[j] = ep[i + j];
        #pragma unroll
        for (int j = 0; j < 8; ++j) P[j] = prew[(size_t)(E[j] >> 16) * 64 + lane];
        #pragma unroll
        for (int j = 0; j < 8; ++j) {
            float w = bflo(E[j]);
            ax = fmaf(w, bflo(P[j]), ax);
            ay = fmaf(w, bfhi(P[j]), ay);
        }
    }
    if (i + 3 < e) {
        unsigned E[4], P[4];
        #pragma unroll
        for (int j = 0; j < 4; ++j) E[j] = ep[i + j];
        #pragma unroll
        for (int j = 0; j < 4; ++j) P[j] = prew[(size_t)(E[j] >> 16) * 64 + lane];
        #pragma unroll
        for (int j = 0; j < 4; ++j) {
            float w = bflo(E[j]);
            ax = fmaf(w, bflo(P[j]), ax);
            ay = fmaf(w, bfhi(P[j]), ay);
        }
        i += 4;
    }
    for (; i < e; ++i) {
        unsigned E = ep[i];
        float w = bflo(E);
        unsigned p = prew[(size_t)(E >> 16) * 64 + lane];
        ax = fmaf(w, bflo(p), ax);
        ay = fmaf(w, bfhi(p), ay);
    }
}

__global__ __launch_bounds__(256) void gather_fused4(const int* __restrict__ off_base,
                                                     const unsigned* __restrict__ ep_base,
                                                     const unsigned short* __restrict__ pre0,
                                                     const unsigned short* __restrict__ pre1,
                                                     float* __restrict__ out, int n_rows) {
    const int lane = threadIdx.x & 63;
    const int wid  = threadIdx.x >> 6;
    const int wpg  = 4 * gridDim.x;
    const unsigned* ep1b = ep_base + N_EDGES;
    const int* o1 = off_base + (N_NODES + 1);
    const unsigned* pre0w = (const unsigned*)pre0;
    const unsigned* pre1w = (const unsigned*)pre1;
    f32x2* out2 = (f32x2*)out;
    for (int r = blockIdx.x * 4 + wid; r < n_rows; r += wpg) {
        float ax0 = 0.f, ay0 = 0.f, ax1 = 0.f, ay1 = 0.f;
        int i0 = __builtin_amdgcn_readfirstlane(off_base[r]);
        int e0 = __builtin_amdgcn_readfirstlane(off_base[r + 1]);
        int i1 = __builtin_amdgcn_readfirstlane(o1[r]);
        int e1 = __builtin_amdgcn_readfirstlane(o1[r + 1]);
        while (i0 + 7 < e0 && i1 + 7 < e1) {
            unsigned E0[8], E1[8], P0[8], P1[8];
            #pragma unroll
            for (int j = 0; j < 8; ++j) { E0[j] = ep_base[i0 + j]; E1[j] = ep1b[i1 + j]; }
            #pragma unroll
            for (int j = 0; j < 8; ++j) {
                P0[j] = pre0w[(size_t)(E0[j] >> 16) * 64 + lane];
                P1[j] = pre1w[(size_t)(E1[j] >> 16) * 64 + lane];
            }
            #pragma unroll
            for (int j = 0; j < 8; ++j) {
                float w0 = bflo(E0[j]);
                float w1 = bflo(E1[j]);
                ax0 = fmaf(w0, bflo(P0[j]), ax0);
                ay0 = fmaf(w0, bfhi(P0[j]), ay0);
                ax1 = fmaf(w1, bflo(P1[j]), ax1);
                ay1 = fmaf(w1, bfhi(P1[j]), ay1);
            }
            i0 += 8; i1 += 8;
        }
        row_acc4(ep_base, pre0w, i0, e0, lane, ax0, ay0);
        row_acc4(ep1b,    pre1w, i1, e1, lane, ax1, ay1);
        f32x2 o;
        o.x = fmaxf(ax0 + ax1, 0.f);
        o.y = fmaxf(ay0 + ay1, 0.f);
        __builtin_nontemporal_store(o, &out2[(size_t)r * 64 + lane]);
    }
}

// ======================= fallback path (proven pieces, int2 ep) =======================
__global__ __launch_bounds__(256) void wt_build(const float* __restrict__ w,
                                                unsigned short* __restrict__ wt) {
    int i = blockIdx.x * 256 + threadIdx.x;
    if (i < 2 * D * D) {
        int s = i >> 14, rem = i & 16383, c = rem >> 7, k = rem & 127;
        wt[i] = f2bf(w[s * D * D + k * D + c]);
    }
}

__device__ __forceinline__ void row_acc(const int2* __restrict__ ep,
                                        const unsigned short* __restrict__ pre,
                                        int b, int e, int lane, float& ax, float& ay) {
    int i = b;
    for (; i + 7 < e; i += 8) {
        int2 E[8];
        unsigned P[8];
        #pragma unroll
        for (int j = 0; j < 8; ++j) E[j] = ep[i + j];
        #pragma unroll
        for (int j = 0; j < 8; ++j) P[j] = *(const unsigned*)(pre + (size_t)E[j].x * D + 2 * lane);
        #pragma unroll
        for (int j = 0; j < 8; ++j) {
            float w = __int_as_float(E[j].y);
            ax = fmaf(w, bflo(P[j]), ax);
            ay = fmaf(w, bfhi(P[j]), ay);
        }
    }
    for (; i < e; ++i) {
        int2 e0 = ep[i];
        float w = __int_as_float(e0.y);
        unsigned p = *(const unsigned*)(pre + (size_t)e0.x * D + 2 * lane);
        ax = fmaf(w, bflo(p), ax);
        ay = fmaf(w, bfhi(p), ay);
    }
}

__global__ __launch_bounds__(256) void gather_fused(const int* __restrict__ off_base,
                                                    const int2* __restrict__ ep_base,
                                                    const unsigned short* __restrict__ pre0,
                                                    const unsigned short* __restrict__ pre1,
                                                    float* __restrict__ out, int n_rows) {
    const int lane = threadIdx.x & 63;
    const int wid  = threadIdx.x >> 6;
    const int wpg  = 4 * gridDim.x;
    const int2* ep1b = ep_base + N_EDGES;
    const int* o1 = off_base + (N_NODES + 1);
    float2* out2 = (float2*)out;
    for (int r = blockIdx.x * 4 + wid; r < n_rows; r += wpg) {
        float ax0 = 0.f, ay0 = 0.f, ax1 = 0.f, ay1 = 0.f;
        row_acc(ep_base, pre0, off_base[r], off_base[r + 1], lane, ax0, ay0);
        row_acc(ep1b,    pre1, o1[r], o1[r + 1], lane, ax1, ay1);
        float2 o;
        o.x = fmaxf(ax0 + ax1, 0.f);
        o.y = fmaxf(ay0 + ay1, 0.f);
        out2[(size_t)r * 64 + lane] = o;
    }
}

__global__ __launch_bounds__(256) void gemm_mfma2(const float* __restrict__ x,
                                                  const unsigned short* __restrict__ wt,
                                                  unsigned short* __restrict__ pre0,
                                                  unsigned short* __restrict__ pre1, int n_rows) {
    gemm_body<2>(x, wt, pre0, pre1, n_rows, blockIdx.x);
}
__global__ __launch_bounds__(256) void gemm_mfma1(const float* __restrict__ x,
                                                  const unsigned short* __restrict__ wt,
                                                  unsigned short* __restrict__ pre, int n_rows) {
    gemm_body<1>(x, wt, pre, pre, n_rows, blockIdx.x);
}

__global__ __launch_bounds__(256) void hist_rank(const int* __restrict__ r0,
                                                 const int* __restrict__ r1,
                                                 int* __restrict__ cnt_base,
                                                 int* __restrict__ rank_base, int n_edges) {
    int s = blockIdx.y;
    const int* r = s ? r1 : r0;
    int* cnt  = cnt_base + s * N_NODES;
    int* rank = rank_base + (size_t)s * N_EDGES;
    for (int e = blockIdx.x * 256 + threadIdx.x; e < n_edges; e += gridDim.x * 256)
        rank[e] = atomicAdd(&cnt[r[e]], 1);
}

__global__ __launch_bounds__(256) void scanA(const int* __restrict__ cnt_base,
                                             int* __restrict__ bsum) {
    int s = blockIdx.y;
    int i = blockIdx.x * 256 + threadIdx.x;
    int v = (i < N_NODES) ? cnt_base[s * N_NODES + i] : 0;
    const int lane = threadIdx.x & 63;
    const int wid  = threadIdx.x >> 6;
    __shared__ int ws[4];
    #pragma unroll
    for (int off = 32; off > 0; off >>= 1) v += __shfl_down(v, off);
    if (lane == 0) ws[wid] = v;
    __syncthreads();
    if (threadIdx.x == 0)
        bsum[s * SCAN_BLOCKS + blockIdx.x] = ws[0] + ws[1] + ws[2] + ws[3];
}

__global__ __launch_bounds__(256) void scanC2(const int* __restrict__ cnt_base,
                                              const int* __restrict__ bsum,
                                              int* __restrict__ off_base) {
    int s = blockIdx.y;
    int t = threadIdx.x;
    const int lane = t & 63;
    const int wid  = t >> 6;
    __shared__ int ws[4];
    __shared__ int base_s;
    int bv = (t < (int)blockIdx.x && t < SCAN_BLOCKS) ? bsum[s * SCAN_BLOCKS + t] : 0;
    #pragma unroll
    for (int off = 32; off > 0; off >>= 1) bv += __shfl_down(bv, off);
    if (lane == 0) ws[wid] = bv;
    __syncthreads();
    if (t == 0) base_s = ws[0] + ws[1] + ws[2] + ws[3];
    __syncthreads();
    int base = base_s;
    __syncthreads();
    int i = blockIdx.x * 256 + t;
    int v = (i < N_NODES) ? cnt_base[s * N_NODES + i] : 0;
    int incl = v;
    #pragma unroll
    for (int off = 1; off < 64; off <<= 1) {
        int tv = __shfl_up(incl, off);
        if (lane >= off) incl += tv;
    }
    if (lane == 63) ws[wid] = incl;
    __syncthreads();
    int wbase = 0;
    #pragma unroll
    for (int j = 0; j < 4; ++j) wbase += (j < wid) ? ws[j] : 0;
    int* off = off_base + s * (N_NODES + 1);
    if (i < N_NODES)
        off[i] = base + wbase + incl - v;
    if (blockIdx.x == 0 && t == 0)
        off[N_NODES] = N_EDGES;
}

__global__ __launch_bounds__(256) void scatter_csr(const int* __restrict__ r0, const int* __restrict__ c0,
                                                   const float* __restrict__ v0,
                                                   const int* __restrict__ r1, const int* __restrict__ c1,
                                                   const float* __restrict__ v1,
                                                   const int* __restrict__ off_base,
                                                   const int* __restrict__ rank_base,
                                                   int2* __restrict__ ep_base, int n_edges) {
    int s = blockIdx.y;
    const int*   r    = s ? r1 : r0;
    const int*   c    = s ? c1 : c0;
    const float* v    = s ? v1 : v0;
    const int*   off  = off_base + s * (N_NODES + 1);
    const int*   rank = rank_base + (size_t)s * N_EDGES;
    int2* ep = ep_base + (size_t)s * N_EDGES;
    for (int e = blockIdx.x * 256 + threadIdx.x; e < n_edges; e += gridDim.x * 256) {
        int p = off[r[e]] + rank[e];
        int2 rec;
        rec.x = c[e];
        rec.y = __float_as_int(v[e]);
        ep[p] = rec;
    }
}

template<int ACCUM_RELU>
__global__ __launch_bounds__(256) void gather_one(const int* __restrict__ off,
                                                  const int2* __restrict__ ep,
                                                  const unsigned short* __restrict__ pre,
                                                  float* __restrict__ out, int n_rows) {
    const int lane = threadIdx.x & 63;
    const int wid  = threadIdx.x >> 6;
    const int wpg  = 4 * gridDim.x;
    float2* out2 = (float2*)out;
    for (int r = blockIdx.x * 4 + wid; r < n_rows; r += wpg) {
        float ax = 0.f, ay = 0.f;
        row_acc(ep, pre, off[r], off[r + 1], lane, ax, ay);
        float2 o;
        if (ACCUM_RELU) {
            float2 prev = out2[(size_t)r * 64 + lane];
            o.x = fmaxf(prev.x + ax, 0.f);
            o.y = fmaxf(prev.y + ay, 0.f);
        } else {
            o.x = ax; o.y = ay;
        }
        out2[(size_t)r * 64 + lane] = o;
    }
}

extern "C" void kernel_launch(void* const* d_in, const int* in_sizes, int n_in,
                              void* d_out, int out_size, void* d_ws, size_t ws_size,
                              hipStream_t stream) {
    const float* x       = (const float*)d_in[0];
    const float* weights = (const float*)d_in[1];
    const int*   ei0     = (const int*)d_in[2];
    const float* v0      = (const float*)d_in[3];
    const int*   ei1     = (const int*)d_in[4];
    const float* v1      = (const float*)d_in[5];
    float* out = (float*)d_out;

    dim3 blk(256);
    const size_t PRE_B = (size_t)N_NODES * D * sizeof(unsigned short);  // 12.8 MB
    const size_t WT_B  = (size_t)2 * D * D * sizeof(unsigned short);    // 64 KB
    const size_t H_B   = (size_t)2 * NB1 * BINS * 4;                    // 100 KB
    const size_t BB_B  = (size_t)2 * (BINS + 1) * 4;
    const size_t OFF_B = (size_t)2 * (N_NODES + 1) * 4;
    const size_t E8    = (size_t)2 * N_EDGES * sizeof(int2);            // 12.8 MB
    const size_t E4    = (size_t)2 * N_EDGES * 4;                       // 6.4 MB

    char* wsb = (char*)d_ws;
    size_t needNew = 2 * PRE_B + WT_B + H_B + BB_B + OFF_B + E8 + E4;
    size_t needA1 = 2 * PRE_B + WT_B
                  + (size_t)(2 * (N_NODES + 1) + 2 * N_NODES + 2 * SCAN_BLOCKS) * 4
                  + E8 + (size_t)2 * N_EDGES * 4;

    if (ws_size >= needNew) {
        unsigned short* pre0 = (unsigned short*)wsb;
        unsigned short* pre1 = (unsigned short*)(wsb + PRE_B);
        unsigned short* wt   = (unsigned short*)(wsb + 2 * PRE_B);
        int*  h       = (int*)(wsb + 2 * PRE_B + WT_B);
        int*  binbase = (int*)((char*)h + H_B);
        int*  off     = (int*)((char*)binbase + BB_B);
        int2* rec     = (int2*)((char*)off + OFF_B);
        unsigned* ep  = (unsigned*)(rec + (size_t)2 * N_EDGES);

        p1_count_wt<<<2 * NB1 + WTB, blk, 0, stream>>>(ei0, ei1, h, weights, wt);
        binredscan<<<2, blk, 0, stream>>>(h, binbase);
        blkscan<<<dim3(BINS, 2), dim3(64), 0, stream>>>(h, binbase);
        k_fill_gemm<<<2 * NB1 + GEMM_BLOCKS, blk, 0, stream>>>(
            x, wt, pre0, pre1,
            ei0, ei0 + N_EDGES, v0, ei1, ei1 + N_EDGES, v1,
            h, rec, N_NODES);
        p2_sort<<<dim3(BINS, 2), dim3(512), 0, stream>>>(binbase, rec, ep, off);
        gather_fused4<<<12500, blk, 0, stream>>>(off, ep, pre0, pre1, out, N_NODES);
    } else if (ws_size >= needA1) {
        unsigned short* pre0 = (unsigned short*)wsb;
        unsigned short* pre1 = (unsigned short*)(wsb + PRE_B);
        unsigned short* wt   = (unsigned short*)(wsb + 2 * PRE_B);
        int*  off  = (int*)(wsb + 2 * PRE_B + WT_B);
        int*  cnt  = off + 2 * (N_NODES + 1);
        int*  bsum = cnt + 2 * N_NODES;
        int2* ep   = (int2*)(bsum + 2 * SCAN_BLOCKS);
        int*  rank = (int*)(ep + (size_t)2 * N_EDGES);

        hipMemsetAsync(cnt, 0, (size_t)2 * N_NODES * sizeof(int), stream);
        wt_build<<<128, blk, 0, stream>>>(weights, wt);
        hist_rank<<<dim3(1024, 2), blk, 0, stream>>>(ei0, ei1, cnt, rank, N_EDGES);
        gemm_mfma2<<<GEMM_BLOCKS, blk, 0, stream>>>(x, wt, pre0, pre1, N_NODES);
        scanA<<<dim3(SCAN_BLOCKS, 2), blk, 0, stream>>>(cnt, bsum);
        scanC2<<<dim3(SCAN_BLOCKS, 2), blk, 0, stream>>>(cnt, bsum, off);
        scatter_csr<<<dim3(1024, 2), blk, 0, stream>>>(ei0, ei0 + N_EDGES, v0,
                                                       ei1, ei1 + N_EDGES, v1,
                                                       off, rank, ep, N_EDGES);
        gather_fused<<<12500, blk, 0, stream>>>(off, ep, pre0, pre1, out, N_NODES);
    } else {
        unsigned short* pre = (unsigned short*)wsb;
        unsigned short* wt  = (unsigned short*)(wsb + PRE_B);
        int*  off  = (int*)(wsb + PRE_B + WT_B);
        int*  cnt  = off + (N_NODES + 1);
        int*  bsum = cnt + N_NODES;
        int2* ep   = (int2*)(bsum + SCAN_BLOCKS);
        int*  rank = (int*)pre;

        wt_build<<<128, blk, 0, stream>>>(weights, wt);
        const int* rows[2] = {ei0, ei1};
        const int* cols[2] = {ei0 + N_EDGES, ei1 + N_EDGES};
        const float* vals[2] = {v0, v1};
        for (int s = 0; s < 2; ++s) {
            hipMemsetAsync(cnt, 0, (size_t)N_NODES * sizeof(int), stream);
            hist_rank<<<dim3(1024, 1), blk, 0, stream>>>(rows[s], rows[s], cnt, rank, N_EDGES);
            scanA<<<dim3(SCAN_BLOCKS, 1), blk, 0, stream>>>(cnt, bsum);
            scanC2<<<dim3(SCAN_BLOCKS, 1), blk, 0, stream>>>(cnt, bsum, off);
            scatter_csr<<<dim3(1024, 1), blk, 0, stream>>>(rows[s], cols[s], vals[s],
                                                           rows[s], cols[s], vals[s],
                                                           off, rank, ep, N_EDGES);
            gemm_mfma1<<<GEMM_BLOCKS, blk, 0, stream>>>(x, wt + (size_t)s * D * D, pre, N_NODES);
            if (s == 0)
                gather_one<0><<<12500, blk, 0, stream>>>(off, ep, pre, out, N_NODES);
            else
                gather_one<1><<<12500, blk, 0, stream>>>(off, ep, pre, out, N_NODES);
        }
    }
}